// Round 6
// baseline (432.931 us; speedup 1.0000x reference)
//
#include <hip/hip_runtime.h>
#include <hip/hip_fp16.h>

#define NNODES 4096
#define LWALK 16
#define ODIM 8

typedef unsigned int uint4n __attribute__((ext_vector_type(4)));

// ---------- edge-index dtype detection (int32 vs int64 on device) ----------
__global__ void detect_fmt_k(const void* ei, int E, int* flag) {
    if (blockIdx.x == 0 && threadIdx.x == 0) {
        const long long* p = (const long long*)ei;
        int ok = 1;
        for (int i = 0; i < 64; ++i) {
            long long v = p[i];
            if (v < 0 || v >= NNODES) { ok = 0; break; }
        }
        *flag = ok;  // 1 => int64 layout, 0 => int32 layout
    }
}

__device__ __forceinline__ int load_idx(const void* p, int i, int fmt) {
    if (fmt) return (int)((const long long*)p)[i];
    return ((const int*)p)[i];
}

// ---------- degree + in-degree counts ----------
__global__ void build_deg_cnt_k(const void* ei, int E, int* deg, int* cnt,
                                const int* fmt) {
    int e = blockIdx.x * blockDim.x + threadIdx.x;
    if (e >= E) return;
    int f = *fmt;
    int r = load_idx(ei, e, f);
    int c = load_idx(ei, E + e, f);
    atomicAdd(&deg[r], 1);
    atomicAdd(&cnt[c], 1);
}

// ---------- exclusive scan over padded (multiple-of-8) counts ----------
__global__ void scan_k(const int* __restrict__ cnt, int* __restrict__ rowptr,
                       int* __restrict__ cursor) {
    __shared__ int sm[1024];
    int tid = threadIdx.x;
    int v0 = (cnt[4 * tid + 0] + 7) & ~7;
    int v1 = (cnt[4 * tid + 1] + 7) & ~7;
    int v2 = (cnt[4 * tid + 2] + 7) & ~7;
    int v3 = (cnt[4 * tid + 3] + 7) & ~7;
    int tsum = v0 + v1 + v2 + v3;
    sm[tid] = tsum;
    __syncthreads();
    int val = tsum;
    for (int off = 1; off < 1024; off <<= 1) {
        int t = (tid >= off) ? sm[tid - off] : 0;
        __syncthreads();
        val += t;
        sm[tid] = val;
        __syncthreads();
    }
    int excl = val - tsum;
    int p0 = excl, p1 = excl + v0, p2 = p1 + v1, p3 = p2 + v2;
    rowptr[4 * tid + 0] = p0; rowptr[4 * tid + 1] = p1;
    rowptr[4 * tid + 2] = p2; rowptr[4 * tid + 3] = p3;
    cursor[4 * tid + 0] = p0; cursor[4 * tid + 1] = p1;
    cursor[4 * tid + 2] = p2; cursor[4 * tid + 3] = p3;
    if (tid == 1023) rowptr[4096] = val;
}

// ---------- counting-sort fill of interleaved padded column-CSR ----------
__global__ void fill_csr_k(const void* ei, int E, const int* __restrict__ deg,
                           int* cursor, uint2* __restrict__ epad, const int* fmt) {
    int e = blockIdx.x * blockDim.x + threadIdx.x;
    if (e >= E) return;
    int f = *fmt;
    int r = load_idx(ei, e, f);
    int c = load_idx(ei, E + e, f);
    int pos = atomicAdd(&cursor[c], 1);
    int d = deg[r];
    float v = 1.0f / (float)(d < 1 ? 1 : d);
    epad[pos] = make_uint2((unsigned)r, __float_as_uint(v));
}

// ---------- zero-fill the padding slots (r=0, v=0 -> harmless) ----------
__global__ void pad_fill_k(const int* __restrict__ rowptr,
                           const int* __restrict__ cursor,
                           uint2* __restrict__ epad) {
    int c = blockIdx.x * blockDim.x + threadIdx.x;
    if (c >= NNODES) return;
    for (int p = cursor[c]; p < rowptr[c + 1]; ++p)
        epad[p] = make_uint2(0u, 0u);
}

// ---------- init X0 = I (fp16), fused zero+eye ----------
__global__ void zeroeye_k(uint4n* p) {
    int i = blockIdx.x * blockDim.x + threadIdx.x;  // 2M chunks of 8 halves
    uint4n z = (uint4n)(0u, 0u, 0u, 0u);
    int g0 = i * 8;
    int row = g0 >> 12;
    int d = row - (g0 & 4095);
    if (d >= 0 && d < 8) ((__half*)&z)[d] = __float2half(1.0f);
    p[i] = z;
}

// ---------- XCD-pinned wave-per-row-slab SpMM, diag fused ----------
// One wave handles (c, slab): 64 lanes x 16B = full 512-half slab row.
// c forced wave-uniform (readfirstlane) -> edge reads go scalar (s_load),
// 8 x 1KB gathers in flight.
__global__ __launch_bounds__(256) void spmm_wave_k(
    const __half* __restrict__ X, __half* __restrict__ Y,
    const int* __restrict__ rowptr, const uint2* __restrict__ epad,
    float* __restrict__ rw, int kcol) {
    const int bid = blockIdx.x;          // 8192 blocks x 4 waves
    const int slab = bid & 7;            // XCD pin via round-robin dispatch
    const int lane = threadIdx.x & 63;
    const int c =
        __builtin_amdgcn_readfirstlane((bid >> 3) * 4 + (threadIdx.x >> 6));
    const int colo = slab * 512 + lane * 8;  // half offset within a row
    const __half* Xs = X + colo;

    const int beg = rowptr[c], end = rowptr[c + 1];  // padded to %8 == 0
    float a[8];
#pragma unroll
    for (int u = 0; u < 8; ++u) a[u] = 0.f;

    for (int e = beg; e < end; e += 8) {
        uint2 ed[8];
#pragma unroll
        for (int j = 0; j < 8; ++j) ed[j] = epad[e + j];
        uint4n x[8];
#pragma unroll
        for (int j = 0; j < 8; ++j)
            x[j] = *(const uint4n*)(Xs + (size_t)ed[j].x * NNODES);
#pragma unroll
        for (int j = 0; j < 8; ++j) {
            float v = __uint_as_float(ed[j].y);
            const __half* h = (const __half*)&x[j];
#pragma unroll
            for (int u = 0; u < 8; ++u)
                a[u] = fmaf(__half2float(h[u]), v, a[u]);
        }
    }

    // fused diagonal: Y[c,c] lives in slab c>>9, lane (c&511)>>3, elem c&7
    if ((c >> 9) == slab && lane == ((c & 511) >> 3)) {
        float d = 0.f;
#pragma unroll
        for (int u = 0; u < 8; ++u)
            if ((c & 7) == u) d = a[u];
        rw[c * LWALK + kcol] = d;
    }

    uint4n o;
    __half2* oh = (__half2*)&o;
#pragma unroll
    for (int u = 0; u < 4; ++u) oh[u] = __floats2half2_rn(a[2 * u], a[2 * u + 1]);
    // non-temporal: streaming Y-write must not evict the pinned X slab
    __builtin_nontemporal_store(o, (uint4n*)(Y + (size_t)c * NNODES + colo));
}

// ---------- fused paired diagonals (shares the A-row stream):
// rw[i,col_odd]  += sum_j A[i,j] * B[j,i]   (A=X_m, B=X_{m-1})
// rw[i,col_even] += sum_j A[i,j] * A[j,i]
__global__ __launch_bounds__(256) void pairdiag2_k(
    const __half* __restrict__ A, const __half* __restrict__ B,
    float* __restrict__ rw, int col_odd, int col_even) {
    __shared__ float bt[64][65];  // B^T tile
    __shared__ float ct[64][65];  // A^T tile
    const int i0 = blockIdx.x * 64;
    const int t = threadIdx.x;
    const int li = t >> 2;   // [0,64)
    const int q = t & 3;     // [0,4)
    const int c0 = q * 16;
    const int Jbeg = blockIdx.y * (NNODES / 16);
    const int Jend = Jbeg + (NNODES / 16);
    float accO = 0.f, accE = 0.f;
    for (int J = Jbeg; J < Jend; J += 64) {
        const __half* bp = B + (size_t)(J + li) * NNODES + i0 + c0;
        uint4n b0 = *(const uint4n*)bp;
        uint4n b1 = *(const uint4n*)(bp + 8);
        const __half* cp = A + (size_t)(J + li) * NNODES + i0 + c0;
        uint4n g0 = *(const uint4n*)cp;
        uint4n g1 = *(const uint4n*)(cp + 8);
        __syncthreads();  // protect previous iteration's LDS reads
        const __half* bh0 = (const __half*)&b0;
        const __half* bh1 = (const __half*)&b1;
        const __half* gh0 = (const __half*)&g0;
        const __half* gh1 = (const __half*)&g1;
#pragma unroll
        for (int s = 0; s < 8; ++s) {
            bt[c0 + s][li] = __half2float(bh0[s]);
            bt[c0 + 8 + s][li] = __half2float(bh1[s]);
            ct[c0 + s][li] = __half2float(gh0[s]);
            ct[c0 + 8 + s][li] = __half2float(gh1[s]);
        }
        __syncthreads();
        const __half* ap = A + (size_t)(i0 + li) * NNODES + J + c0;
        uint4n a0 = *(const uint4n*)ap;
        uint4n a1 = *(const uint4n*)(ap + 8);
        const __half* ah0 = (const __half*)&a0;
        const __half* ah1 = (const __half*)&a1;
#pragma unroll
        for (int s = 0; s < 8; ++s) {
            float a = __half2float(ah0[s]);
            accO = fmaf(a, bt[li][c0 + s], accO);
            accE = fmaf(a, ct[li][c0 + s], accE);
        }
#pragma unroll
        for (int s = 0; s < 8; ++s) {
            float a = __half2float(ah1[s]);
            accO = fmaf(a, bt[li][c0 + 8 + s], accO);
            accE = fmaf(a, ct[li][c0 + 8 + s], accE);
        }
    }
    accO += __shfl_xor(accO, 1);
    accO += __shfl_xor(accO, 2);
    accE += __shfl_xor(accE, 1);
    accE += __shfl_xor(accE, 2);
    if (q == 0) {
        atomicAdd(&rw[(i0 + li) * LWALK + col_odd], accO);
        atomicAdd(&rw[(i0 + li) * LWALK + col_even], accE);
    }
}

// ---------- final linear ----------
__global__ void linear_k(const float* __restrict__ rw, const float* __restrict__ W,
                         const float* __restrict__ b, float* __restrict__ out) {
    int i = blockIdx.x * blockDim.x + threadIdx.x;
    if (i >= NNODES * ODIM) return;
    int s = i >> 3, d = i & 7;
    float acc = b[d];
#pragma unroll
    for (int k = 0; k < LWALK; ++k)
        acc = fmaf(rw[s * LWALK + k], W[d * LWALK + k], acc);
    out[i] = acc;
}

extern "C" void kernel_launch(void* const* d_in, const int* in_sizes, int n_in,
                              void* d_out, int out_size, void* d_ws, size_t ws_size,
                              hipStream_t stream) {
    const void* ei = d_in[0];
    int E = in_sizes[0] / 2;
    const float* W = (const float*)d_in[2];
    const float* bias = (const float*)d_in[3];
    float* out = (float*)d_out;

    char* ws = (char*)d_ws;
    size_t off = 0;
    auto alloc = [&](size_t bytes) -> char* {
        char* p = ws + off;
        off = (off + bytes + 255) & ~(size_t)255;
        return p;
    };
    int* flag = (int*)alloc(4);
    int* deg = (int*)alloc(NNODES * 4);
    int* cnt = (int*)alloc(NNODES * 4);
    int* rowptr = (int*)alloc((NNODES + 1) * 4);
    int* cursor = (int*)alloc(NNODES * 4);
    uint2* epad = (uint2*)alloc(((size_t)E + 8 * NNODES) * 8);
    float* rw = (float*)alloc(NNODES * LWALK * 4);
    __half* Xb = (__half*)alloc((size_t)NNODES * NNODES * 2);
    __half* Yb = (__half*)alloc((size_t)NNODES * NNODES * 2);

    (void)hipMemsetAsync(deg, 0, NNODES * 4, stream);
    (void)hipMemsetAsync(cnt, 0, NNODES * 4, stream);
    (void)hipMemsetAsync(rw, 0, NNODES * LWALK * 4, stream);
    detect_fmt_k<<<1, 64, 0, stream>>>(ei, E, flag);
    build_deg_cnt_k<<<(E + 255) / 256, 256, 0, stream>>>(ei, E, deg, cnt, flag);
    scan_k<<<1, 1024, 0, stream>>>(cnt, rowptr, cursor);
    fill_csr_k<<<(E + 255) / 256, 256, 0, stream>>>(ei, E, deg, cursor, epad, flag);
    pad_fill_k<<<(NNODES + 255) / 256, 256, 0, stream>>>(rowptr, cursor, epad);

    // X0 = I
    int nchunks = NNODES * (NNODES / 8);  // 16B chunks
    zeroeye_k<<<nchunks / 256, 256, 0, stream>>>((uint4n*)Xb);

    __half* X = Xb;
    __half* Y = Yb;
    for (int m = 1; m <= 8; ++m) {
        spmm_wave_k<<<NNODES * 8 / 4, 256, 0, stream>>>(X, Y, rowptr, epad, rw,
                                                        m - 1);
        if (m >= 5) {
            dim3 pg(NNODES / 64, 16);
            // odd walk 2m-1 (col 2m-2): sum_j X_m[i,j] * X_{m-1}[j,i]
            // even walk 2m (col 2m-1): sum_j X_m[i,j] * X_m[j,i]
            pairdiag2_k<<<pg, 256, 0, stream>>>(Y, X, rw, 2 * m - 2, 2 * m - 1);
        }
        __half* t = X; X = Y; Y = t;
    }
    linear_k<<<(NNODES * ODIM + 255) / 256, 256, 0, stream>>>(rw, W, bias, out);
}